// Round 1
// baseline (1454.068 us; speedup 1.0000x reference)
//
#include <hip/hip_runtime.h>

#define HID      1024
#define INTER    2048
#define STATE    128
#define NH       32
#define PDIM     64
#define KCONV    4
#define QCH      256
#define CONV_DIM (INTER + 2*STATE)      // 2304
#define DPROJ    (2*INTER + 2*STATE + NH) // 4384
#define BATCH    2
#define SEQ      2048
#define NCHUNK   (SEQ / QCH)            // 8
#define BL       (BATCH * SEQ)          // 4096

// ---------------------------------------------------------------------------
// GEMM  C[M,N] = A[M,K] * W[N,K]^T   (both row-major, K contiguous: "NT")
// 64x64 tile, 16x16 threads, 4x4 microtile, K-tiles of 16.
// ---------------------------------------------------------------------------
__global__ __launch_bounds__(256)
void gemm_nt_f32(const float* __restrict__ A, const float* __restrict__ W,
                 float* __restrict__ C, int M, int N, int Kd) {
    __shared__ float As[16][65];
    __shared__ float Bs[16][65];
    const int bm = blockIdx.y * 64;
    const int bn = blockIdx.x * 64;
    const int t  = threadIdx.x;
    const int tm = t >> 4, tn = t & 15;
    const int lr = t >> 2;          // staging row 0..63
    const int lc = (t & 3) * 4;     // staging k-col 0,4,8,12
    float acc[4][4] = {};
    for (int k0 = 0; k0 < Kd; k0 += 16) {
        float4 av = make_float4(0.f,0.f,0.f,0.f);
        float4 bv = make_float4(0.f,0.f,0.f,0.f);
        if (bm + lr < M) av = *(const float4*)&A[(size_t)(bm + lr) * Kd + k0 + lc];
        if (bn + lr < N) bv = *(const float4*)&W[(size_t)(bn + lr) * Kd + k0 + lc];
        __syncthreads();
        As[lc+0][lr] = av.x; As[lc+1][lr] = av.y; As[lc+2][lr] = av.z; As[lc+3][lr] = av.w;
        Bs[lc+0][lr] = bv.x; Bs[lc+1][lr] = bv.y; Bs[lc+2][lr] = bv.z; Bs[lc+3][lr] = bv.w;
        __syncthreads();
#pragma unroll
        for (int kk = 0; kk < 16; ++kk) {
            float a0[4], b0[4];
#pragma unroll
            for (int i = 0; i < 4; ++i) a0[i] = As[kk][tm*4 + i];
#pragma unroll
            for (int j = 0; j < 4; ++j) b0[j] = Bs[kk][tn*4 + j];
#pragma unroll
            for (int i = 0; i < 4; ++i)
#pragma unroll
                for (int j = 0; j < 4; ++j)
                    acc[i][j] = fmaf(a0[i], b0[j], acc[i][j]);
        }
    }
    for (int i = 0; i < 4; ++i) {
        int r = bm + tm*4 + i;
        if (r >= M) continue;
        for (int j = 0; j < 4; ++j) {
            int cc = bn + tn*4 + j;
            if (cc < N) C[(size_t)r * N + cc] = acc[i][j];
        }
    }
}

// ---------------------------------------------------------------------------
// Depthwise causal conv (K=4) + bias + silu over xBC channels of zxbcdt.
// ---------------------------------------------------------------------------
__global__ void conv_silu_kernel(const float* __restrict__ zx,
                                 const float* __restrict__ conv_w,
                                 const float* __restrict__ conv_b,
                                 float* __restrict__ xbc) {
    int tid = blockIdx.x * blockDim.x + threadIdx.x;
    if (tid >= BL * CONV_DIM) return;
    int c  = tid % CONV_DIM;
    int bl = tid / CONV_DIM;
    int l  = bl % SEQ;
    float acc = conv_b[c];
#pragma unroll
    for (int k = 0; k < KCONV; ++k) {
        int ls = l - (KCONV - 1) + k;
        if (ls >= 0)
            acc = fmaf(zx[(size_t)(bl - (KCONV - 1) + k) * DPROJ + INTER + c],
                       conv_w[c * KCONV + k], acc);
    }
    xbc[(size_t)bl * CONV_DIM + c] = acc / (1.f + expf(-acc));
}

// ---------------------------------------------------------------------------
// dt = softplus(dt_raw + dt_bias); seg = inclusive cumsum(dt * A) per chunk.
// One block per (b, chunk, h), 256 threads = chunk positions.
// ---------------------------------------------------------------------------
__global__ __launch_bounds__(256)
void dtseg_kernel(const float* __restrict__ zx,
                  const float* __restrict__ dt_bias,
                  const float* __restrict__ A_log,
                  float* __restrict__ dt_out,
                  float* __restrict__ seg_out) {
    int bid = blockIdx.x;
    int h = bid & 31, c = (bid >> 5) & 7, b = bid >> 8;
    int i = threadIdx.x;
    int bl = b * SEQ + c * QCH + i;
    float x = zx[(size_t)bl * DPROJ + INTER + CONV_DIM + h] + dt_bias[h];
    float dtv = (x > 20.f) ? x : log1pf(expf(x));
    dt_out[bl * NH + h] = dtv;
    float Ah = -expf(A_log[h]);
    __shared__ float s[QCH];
    s[i] = dtv * Ah;
    __syncthreads();
    for (int off = 1; off < QCH; off <<= 1) {
        float add = (i >= off) ? s[i - off] : 0.f;
        __syncthreads();
        s[i] += add;
        __syncthreads();
    }
    seg_out[bl * NH + h] = s[i];
}

// ---------------------------------------------------------------------------
// CB[bc, i, j] = sum_n C[i,n] * B[j,n] per chunk (only lower tile blocks).
// grid (16, it, jt), 64x64 per block.
// ---------------------------------------------------------------------------
__global__ __launch_bounds__(256)
void cb_kernel(const float* __restrict__ xbc, float* __restrict__ CB) {
    int bc = blockIdx.x;               // b*NCHUNK+c
    int it = blockIdx.y, jt = blockIdx.z;
    if (jt > it) return;
    int b = bc >> 3, c = bc & 7;
    __shared__ float Cts[64][65];
    __shared__ float Bts[64][65];
    int t = threadIdx.x;
    int ti = t >> 4, tj = t & 15;
    float acc[4][4] = {};
    for (int k0 = 0; k0 < STATE; k0 += 64) {
        __syncthreads();
        for (int i = 0; i < 16; ++i) {
            int idx = t + i * 256;
            int r = idx >> 6, kc = idx & 63;
            Cts[r][kc] = xbc[(size_t)(b*SEQ + c*QCH + it*64 + r) * CONV_DIM + INTER + STATE + k0 + kc];
            Bts[r][kc] = xbc[(size_t)(b*SEQ + c*QCH + jt*64 + r) * CONV_DIM + INTER + k0 + kc];
        }
        __syncthreads();
#pragma unroll 16
        for (int k = 0; k < 64; ++k) {
            float cv[4], bv[4];
#pragma unroll
            for (int ii = 0; ii < 4; ++ii) cv[ii] = Cts[4*ti + ii][k];
#pragma unroll
            for (int jj = 0; jj < 4; ++jj) bv[jj] = Bts[4*tj + jj][k];
#pragma unroll
            for (int ii = 0; ii < 4; ++ii)
#pragma unroll
                for (int jj = 0; jj < 4; ++jj)
                    acc[ii][jj] = fmaf(cv[ii], bv[jj], acc[ii][jj]);
        }
    }
    for (int ii = 0; ii < 4; ++ii)
        for (int jj = 0; jj < 4; ++jj)
            CB[((size_t)bc * QCH + it*64 + 4*ti + ii) * QCH + jt*64 + 4*tj + jj] = acc[ii][jj];
}

// ---------------------------------------------------------------------------
// states[b,c,h,p,n] = sum_j B[j,n] * x[j,h,p] * dt[j] * exp(seg_last - seg[j])
// One block per (b,c,h); j-tiles of 64 in LDS.
// ---------------------------------------------------------------------------
__global__ __launch_bounds__(256)
void states_kernel(const float* __restrict__ xbc, const float* __restrict__ dt,
                   const float* __restrict__ seg, float* __restrict__ states) {
    int bid = blockIdx.x;
    int h = bid & 31, c = (bid >> 5) & 7, b = bid >> 8;
    __shared__ float Bsh[64][STATE];   // [j][n] row stride 128 (float2 aligned)
    __shared__ float xws[64][PDIM];    // [j][p]
    int t = threadIdx.x;
    int tp = t >> 4, tn = t & 15;      // p = 4*tp+ii ; n = 2*tn + 32*jj (+d)
    float2 acc[4][4];
    for (int ii = 0; ii < 4; ++ii)
        for (int jj = 0; jj < 4; ++jj) acc[ii][jj] = make_float2(0.f, 0.f);
    float seg_last = seg[(size_t)(b*SEQ + c*QCH + QCH - 1) * NH + h];
    for (int j0 = 0; j0 < QCH; j0 += 64) {
        __syncthreads();
        for (int i = 0; i < 32; ++i) {
            int idx = t + i * 256;
            int r = idx >> 7, col = idx & 127;
            Bsh[r][col] = xbc[(size_t)(b*SEQ + c*QCH + j0 + r) * CONV_DIM + INTER + col];
        }
        for (int i = 0; i < 16; ++i) {
            int idx = t + i * 256;
            int r = idx >> 6, col = idx & 63;
            int bl = b*SEQ + c*QCH + j0 + r;
            float d = dt[bl * NH + h];
            float dec = expf(seg_last - seg[bl * NH + h]);
            xws[r][col] = xbc[(size_t)bl * CONV_DIM + h * PDIM + col] * d * dec;
        }
        __syncthreads();
#pragma unroll 8
        for (int j = 0; j < 64; ++j) {
            float xv[4];
#pragma unroll
            for (int ii = 0; ii < 4; ++ii) xv[ii] = xws[j][4*tp + ii];
            float2 bv[4];
#pragma unroll
            for (int jj = 0; jj < 4; ++jj) bv[jj] = *(const float2*)&Bsh[j][2*tn + 32*jj];
#pragma unroll
            for (int ii = 0; ii < 4; ++ii)
#pragma unroll
                for (int jj = 0; jj < 4; ++jj) {
                    acc[ii][jj].x = fmaf(xv[ii], bv[jj].x, acc[ii][jj].x);
                    acc[ii][jj].y = fmaf(xv[ii], bv[jj].y, acc[ii][jj].y);
                }
        }
    }
    size_t base = ((((size_t)b * NCHUNK + c) * NH + h) * PDIM) * STATE;
    for (int ii = 0; ii < 4; ++ii)
        for (int jj = 0; jj < 4; ++jj) {
            int p = 4*tp + ii, n = 2*tn + 32*jj;
            *(float2*)&states[base + (size_t)p * STATE + n] = acc[ii][jj];
        }
}

// ---------------------------------------------------------------------------
// In-place inter-chunk scan: states[c] <- carry;  carry = carry*dec[c]+st
// ---------------------------------------------------------------------------
__global__ void scan_kernel(float* __restrict__ states, const float* __restrict__ seg) {
    int tid = blockIdx.x * blockDim.x + threadIdx.x;   // B*NH*PDIM*STATE = 2^19
    int n = tid & 127, p = (tid >> 7) & 63, h = (tid >> 13) & 31, b = tid >> 18;
    float carry = 0.f;
    for (int c = 0; c < NCHUNK; ++c) {
        size_t idx = ((((size_t)b * NCHUNK + c) * NH + h) * PDIM + p) * STATE + n;
        float st = states[idx];
        states[idx] = carry;
        float dec = expf(seg[(size_t)(b*SEQ + c*QCH + QCH - 1) * NH + h]);
        carry = carry * dec + st;
    }
}

// ---------------------------------------------------------------------------
// Yd: y[i,h,p] = sum_{j<=i} CB[i,j]*exp(seg[i]-seg[j])*x[j,h,p]*dt[j] + D[h]*x[i,h,p]
// block = (b, c, h, i-tile of 64)
// ---------------------------------------------------------------------------
__global__ __launch_bounds__(256)
void yd_kernel(const float* __restrict__ xbc, const float* __restrict__ dt,
               const float* __restrict__ seg, const float* __restrict__ CB,
               const float* __restrict__ Dv, float* __restrict__ y) {
    int bid = blockIdx.x;
    int it = bid & 3, h = (bid >> 2) & 31, c = (bid >> 7) & 7, b = bid >> 10;
    int i0 = it * 64;
    __shared__ float Ls[64][65];
    __shared__ float xdts[64][64];
    __shared__ float segi_s[64], segj_s[64];
    int t = threadIdx.x;
    int ti = t >> 4, tp = t & 15;
    float acc[4][4] = {};
    if (t < 64) segi_s[t] = seg[(size_t)(b*SEQ + c*QCH + i0 + t) * NH + h];
    for (int j0 = 0; j0 <= i0; j0 += 64) {
        __syncthreads();
        if (t < 64) segj_s[t] = seg[(size_t)(b*SEQ + c*QCH + j0 + t) * NH + h];
        for (int i = 0; i < 16; ++i) {
            int idx = t + i * 256;
            int r = idx >> 6, col = idx & 63;
            int bl = b*SEQ + c*QCH + j0 + r;
            xdts[r][col] = xbc[(size_t)bl * CONV_DIM + h * PDIM + col] * dt[bl * NH + h];
        }
        __syncthreads();
        for (int i = 0; i < 16; ++i) {
            int idx = t + i * 256;
            int r = idx >> 6, col = idx & 63;   // r: i-row, col: j
            float v = 0.f;
            if (j0 + col <= i0 + r)
                v = CB[((size_t)(b*NCHUNK + c) * QCH + i0 + r) * QCH + j0 + col]
                    * expf(segi_s[r] - segj_s[col]);
            Ls[r][col] = v;
        }
        __syncthreads();
#pragma unroll 8
        for (int j = 0; j < 64; ++j) {
            float lv[4], xv[4];
#pragma unroll
            for (int ii = 0; ii < 4; ++ii) lv[ii] = Ls[4*ti + ii][j];
#pragma unroll
            for (int pp = 0; pp < 4; ++pp) xv[pp] = xdts[j][4*tp + pp];
#pragma unroll
            for (int ii = 0; ii < 4; ++ii)
#pragma unroll
                for (int pp = 0; pp < 4; ++pp)
                    acc[ii][pp] = fmaf(lv[ii], xv[pp], acc[ii][pp]);
        }
    }
    float Dh = Dv[h];
    for (int ii = 0; ii < 4; ++ii) {
        int bl = b*SEQ + c*QCH + i0 + 4*ti + ii;
        for (int pp = 0; pp < 4; ++pp) {
            int p = 4*tp + pp;
            float xval = xbc[(size_t)bl * CONV_DIM + h * PDIM + p];
            y[(size_t)bl * INTER + h * PDIM + p] = acc[ii][pp] + Dh * xval;
        }
    }
}

// ---------------------------------------------------------------------------
// Yo: y[i,h,p] += exp(seg[i,h]) * sum_n C[i,n] * prev[b,c,h,p,n]
// block = (b,c,h); prev staged transposed in LDS; i-tiles of 32.
// ---------------------------------------------------------------------------
__global__ __launch_bounds__(256)
void yo_kernel(const float* __restrict__ xbc, const float* __restrict__ seg,
               const float* __restrict__ prev, float* __restrict__ y) {
    int bid = blockIdx.x;
    int h = bid & 31, c = (bid >> 5) & 7, b = bid >> 8;
    __shared__ float prevT[STATE][PDIM + 1];   // [n][p]
    __shared__ float Cs[32][STATE + 1];        // [i][n]
    int t = threadIdx.x;
    size_t pbase = ((((size_t)b * NCHUNK + c) * NH + h) * PDIM) * STATE;
    for (int i = 0; i < 32; ++i) {
        int idx = t + i * 256;
        int n = idx & 127, p = idx >> 7;
        prevT[n][p] = prev[pbase + (size_t)p * STATE + n];
    }
    int ti = t >> 5, tp = t & 31;   // i = i0+4*ti+ii (32 rows), p = 2*tp+pp
    for (int i0 = 0; i0 < QCH; i0 += 32) {
        __syncthreads();
        for (int i = 0; i < 16; ++i) {
            int idx = t + i * 256;
            int n = idx & 127, r = idx >> 7;
            Cs[r][n] = xbc[(size_t)(b*SEQ + c*QCH + i0 + r) * CONV_DIM + INTER + STATE + n];
        }
        __syncthreads();
        float acc[4][2] = {};
#pragma unroll 4
        for (int n = 0; n < STATE; ++n) {
            float cv[4], pv[2];
#pragma unroll
            for (int ii = 0; ii < 4; ++ii) cv[ii] = Cs[4*ti + ii][n];
#pragma unroll
            for (int pp = 0; pp < 2; ++pp) pv[pp] = prevT[n][2*tp + pp];
#pragma unroll
            for (int ii = 0; ii < 4; ++ii)
#pragma unroll
                for (int pp = 0; pp < 2; ++pp)
                    acc[ii][pp] = fmaf(cv[ii], pv[pp], acc[ii][pp]);
        }
        for (int ii = 0; ii < 4; ++ii) {
            int bl = b*SEQ + c*QCH + i0 + 4*ti + ii;
            float e = expf(seg[(size_t)bl * NH + h]);
            for (int pp = 0; pp < 2; ++pp) {
                int p = 2*tp + pp;
                y[(size_t)bl * INTER + h * PDIM + p] += e * acc[ii][pp];
            }
        }
    }
}

// ---------------------------------------------------------------------------
// yg = y * silu(z); RMS-norm over INTER; * norm_weight.  (in place on y)
// ---------------------------------------------------------------------------
__global__ __launch_bounds__(256)
void gatenorm_kernel(float* __restrict__ y, const float* __restrict__ zx,
                     const float* __restrict__ nw) {
    int bl = blockIdx.x;
    int t = threadIdx.x;
    float g[8];
    float ss = 0.f;
#pragma unroll
    for (int i = 0; i < 8; ++i) {
        int cidx = t + 256 * i;
        float yv = y[(size_t)bl * INTER + cidx];
        float zv = zx[(size_t)bl * DPROJ + cidx];
        float gg = yv * (zv / (1.f + expf(-zv)));
        g[i] = gg;
        ss += gg * gg;
    }
    for (int off = 32; off > 0; off >>= 1) ss += __shfl_xor(ss, off, 64);
    __shared__ float red[4];
    if ((t & 63) == 0) red[t >> 6] = ss;
    __syncthreads();
    float tot = red[0] + red[1] + red[2] + red[3];
    float scale = rsqrtf(tot / INTER + 1e-6f);
#pragma unroll
    for (int i = 0; i < 8; ++i) {
        int cidx = t + 256 * i;
        y[(size_t)bl * INTER + cidx] = g[i] * scale * nw[cidx];
    }
}

// ---------------------------------------------------------------------------
extern "C" void kernel_launch(void* const* d_in, const int* in_sizes, int n_in,
                              void* d_out, int out_size, void* d_ws, size_t ws_size,
                              hipStream_t stream) {
    const float* hidden     = (const float*)d_in[0];
    const float* in_proj_w  = (const float*)d_in[1];
    const float* conv_w     = (const float*)d_in[2];
    const float* conv_b     = (const float*)d_in[3];
    const float* dt_bias    = (const float*)d_in[4];
    const float* A_log      = (const float*)d_in[5];
    const float* Dv         = (const float*)d_in[6];
    const float* norm_w     = (const float*)d_in[7];
    const float* out_proj_w = (const float*)d_in[8];
    float* out = (float*)d_out;

    float* ws     = (float*)d_ws;
    float* zx     = ws;                                    // BL*DPROJ      = 17,956,864
    float* xbc    = zx  + (size_t)BL * DPROJ;              // BL*CONV_DIM   =  9,437,184
    float* dtb    = xbc + (size_t)BL * CONV_DIM;           // BL*NH         =    131,072
    float* segb   = dtb + (size_t)BL * NH;                 // BL*NH         =    131,072
    float* CB     = segb + (size_t)BL * NH;                // 16*QCH*QCH    =  1,048,576
    float* states = CB  + (size_t)BATCH*NCHUNK*QCH*QCH;    // 2*8*32*64*128 = 16,777,216
    float* y      = states + (size_t)BATCH*NCHUNK*NH*PDIM*STATE; // BL*INTER = 8,388,608
    // total ~53.9M floats = 215.5 MB

    // 1. in_proj: zx = hidden @ in_proj_w^T
    gemm_nt_f32<<<dim3((DPROJ + 63) / 64, BL / 64), 256, 0, stream>>>(
        hidden, in_proj_w, zx, BL, DPROJ, HID);
    // 2. depthwise conv + silu
    conv_silu_kernel<<<(BL * CONV_DIM) / 256, 256, 0, stream>>>(zx, conv_w, conv_b, xbc);
    // 3. dt + per-chunk cumsum
    dtseg_kernel<<<BATCH * NCHUNK * NH, 256, 0, stream>>>(zx, dt_bias, A_log, dtb, segb);
    // 4. CB per chunk
    cb_kernel<<<dim3(BATCH * NCHUNK, 4, 4), 256, 0, stream>>>(xbc, CB);
    // 5. chunk-local states
    states_kernel<<<BATCH * NCHUNK * NH, 256, 0, stream>>>(xbc, dtb, segb, states);
    // 6. inter-chunk scan (in place: states -> prev-states)
    scan_kernel<<<(BATCH * NH * PDIM * STATE) / 256, 256, 0, stream>>>(states, segb);
    // 7. diagonal (within-chunk) contribution + D*x
    yd_kernel<<<BATCH * NCHUNK * NH * 4, 256, 0, stream>>>(xbc, dtb, segb, CB, Dv, y);
    // 8. off-diagonal (state) contribution
    yo_kernel<<<BATCH * NCHUNK * NH, 256, 0, stream>>>(xbc, segb, states, y);
    // 9. gate + RMS norm
    gatenorm_kernel<<<BL, 256, 0, stream>>>(y, zx, norm_w);
    // 10. out_proj -> d_out
    gemm_nt_f32<<<dim3(HID / 64, BL / 64), 256, 0, stream>>>(
        y, out_proj_w, out, BL, HID, INTER);
}

// Round 2
// 522.293 us; speedup vs baseline: 2.7840x; 2.7840x over previous
//
#include <hip/hip_runtime.h>

#define HID      1024
#define INTER    2048
#define STATE    128
#define NH       32
#define PDIM     64
#define KCONV    4
#define QCH      256
#define CONV_DIM (INTER + 2*STATE)      // 2304
#define DPROJ    (2*INTER + 2*STATE + NH) // 4384
#define DPROJ_PAD 4480                  // next multiple of 128
#define BATCH    2
#define SEQ      2048
#define NCHUNK   (SEQ / QCH)            // 8
#define BL       (BATCH * SEQ)          // 4096

typedef unsigned short u16;
typedef u16 u16x8 __attribute__((ext_vector_type(8)));
typedef float f32x4 __attribute__((ext_vector_type(4)));
typedef __bf16 bf16x8 __attribute__((ext_vector_type(8)));

static __device__ __forceinline__ u16 f2bf(float f) {
    unsigned int u = __float_as_uint(f);
    unsigned int r = (u + 0x7FFFu + ((u >> 16) & 1u)) >> 16;
    return (u16)r;
}

static __device__ __forceinline__ void gload_lds16(const void* g, void* l) {
    __builtin_amdgcn_global_load_lds(
        (const __attribute__((address_space(1))) void*)g,
        (__attribute__((address_space(3))) void*)l, 16, 0, 0);
}

// ---------------------------------------------------------------------------
// f32 -> bf16 conversion, 8 elems/thread; zero-fills [n, ntot).
// ---------------------------------------------------------------------------
__global__ __launch_bounds__(256)
void cvt_bf16(const float* __restrict__ src, u16* __restrict__ dst,
              long n, long ntot) {
    long i = ((long)blockIdx.x * 256 + threadIdx.x) * 8;
    if (i >= ntot) return;
    u16x8 o;
    if (i < n) {
        float4 a = *(const float4*)&src[i];
        float4 b = *(const float4*)&src[i + 4];
        o[0] = f2bf(a.x); o[1] = f2bf(a.y); o[2] = f2bf(a.z); o[3] = f2bf(a.w);
        o[4] = f2bf(b.x); o[5] = f2bf(b.y); o[6] = f2bf(b.z); o[7] = f2bf(b.w);
    } else {
        o = (u16x8)0;
    }
    *(u16x8*)&dst[i] = o;
}

// ---------------------------------------------------------------------------
// bf16 MFMA GEMM (m97 structure):  C[M,Nstride](f32) = A[M,K] * W[Npad,K]^T
// 128x128 tile, BK=32, 4 waves (2x2), 16x16x32 MFMA, global_load_lds(16B).
// ---------------------------------------------------------------------------
__global__ __launch_bounds__(256)
void gemm_nt_bf16(const __bf16* __restrict__ A, const __bf16* __restrict__ W,
                  float* __restrict__ C, int M, int Nstride, int Nreal, int K) {
    __shared__ __attribute__((aligned(16))) __bf16 As[128 * 32];
    __shared__ __attribute__((aligned(16))) __bf16 Ws[128 * 32];
    const int bm = blockIdx.y * 128;
    const int bn = blockIdx.x * 128;
    const int t = threadIdx.x;
    const int lane = t & 63;
    const int wave = t >> 6;
    const int wr = wave >> 1, wc = wave & 1;
    const int fr = lane & 15;       // fragment row (A) / col (B)
    const int fq = lane >> 4;       // k-group: k = 8*fq + j ; C-row quad
    f32x4 acc[4][4];
#pragma unroll
    for (int m = 0; m < 4; ++m)
#pragma unroll
        for (int n = 0; n < 4; ++n) acc[m][n] = 0;

    const int r0 = t >> 2;          // staging row 0..63
    const int sg = (t & 3) * 8;     // staging k-seg (8 bf16 = 16B)
    const __bf16* Ag = A + (size_t)(bm + r0) * K + sg;
    const __bf16* Wg = W + (size_t)(bn + r0) * K + sg;

    for (int k0 = 0; k0 < K; k0 += 32) {
        gload_lds16(Ag + k0,                  &As[t * 8]);
        gload_lds16(Ag + (size_t)64 * K + k0, &As[2048 + t * 8]);
        gload_lds16(Wg + k0,                  &Ws[t * 8]);
        gload_lds16(Wg + (size_t)64 * K + k0, &Ws[2048 + t * 8]);
        __syncthreads();   // drains vmcnt(0): gload_lds complete
        bf16x8 af[4], bw[4];
#pragma unroll
        for (int m = 0; m < 4; ++m)
            af[m] = *(const bf16x8*)&As[(wr * 64 + m * 16 + fr) * 32 + fq * 8];
#pragma unroll
        for (int n = 0; n < 4; ++n)
            bw[n] = *(const bf16x8*)&Ws[(wc * 64 + n * 16 + fr) * 32 + fq * 8];
#pragma unroll
        for (int m = 0; m < 4; ++m)
#pragma unroll
            for (int n = 0; n < 4; ++n)
                acc[m][n] = __builtin_amdgcn_mfma_f32_16x16x32_bf16(
                    af[m], bw[n], acc[m][n], 0, 0, 0);
        __syncthreads();
    }
#pragma unroll
    for (int m = 0; m < 4; ++m)
#pragma unroll
        for (int n = 0; n < 4; ++n) {
            int col = bn + wc * 64 + n * 16 + fr;
            if (col >= Nreal) continue;
            int row0 = bm + wr * 64 + m * 16 + fq * 4;
#pragma unroll
            for (int r = 0; r < 4; ++r)
                C[(size_t)(row0 + r) * Nstride + col] = acc[m][n][r];
        }
}

// ---------------------------------------------------------------------------
// Depthwise causal conv (K=4) + bias + silu over xBC channels of zxbcdt.
// ---------------------------------------------------------------------------
__global__ void conv_silu_kernel(const float* __restrict__ zx,
                                 const float* __restrict__ conv_w,
                                 const float* __restrict__ conv_b,
                                 float* __restrict__ xbc) {
    int tid = blockIdx.x * blockDim.x + threadIdx.x;
    if (tid >= BL * CONV_DIM) return;
    int c  = tid % CONV_DIM;
    int bl = tid / CONV_DIM;
    int l  = bl % SEQ;
    float acc = conv_b[c];
#pragma unroll
    for (int k = 0; k < KCONV; ++k) {
        int ls = l - (KCONV - 1) + k;
        if (ls >= 0)
            acc = fmaf(zx[(size_t)(bl - (KCONV - 1) + k) * DPROJ + INTER + c],
                       conv_w[c * KCONV + k], acc);
    }
    xbc[(size_t)bl * CONV_DIM + c] = acc / (1.f + expf(-acc));
}

// ---------------------------------------------------------------------------
// dt = softplus(dt_raw + dt_bias); seg = inclusive cumsum(dt * A) per chunk.
// ---------------------------------------------------------------------------
__global__ __launch_bounds__(256)
void dtseg_kernel(const float* __restrict__ zx,
                  const float* __restrict__ dt_bias,
                  const float* __restrict__ A_log,
                  float* __restrict__ dt_out,
                  float* __restrict__ seg_out) {
    int bid = blockIdx.x;
    int h = bid & 31, c = (bid >> 5) & 7, b = bid >> 8;
    int i = threadIdx.x;
    int bl = b * SEQ + c * QCH + i;
    float x = zx[(size_t)bl * DPROJ + INTER + CONV_DIM + h] + dt_bias[h];
    float dtv = (x > 20.f) ? x : log1pf(expf(x));
    dt_out[bl * NH + h] = dtv;
    float Ah = -expf(A_log[h]);
    __shared__ float s[QCH];
    s[i] = dtv * Ah;
    __syncthreads();
    for (int off = 1; off < QCH; off <<= 1) {
        float add = (i >= off) ? s[i - off] : 0.f;
        __syncthreads();
        s[i] += add;
        __syncthreads();
    }
    seg_out[bl * NH + h] = s[i];
}

// ---------------------------------------------------------------------------
// CB[bc, i, j] = sum_n C[i,n] * B[j,n] per chunk (lower tile blocks only).
// ---------------------------------------------------------------------------
__global__ __launch_bounds__(256)
void cb_kernel(const float* __restrict__ xbc, float* __restrict__ CB) {
    int bc = blockIdx.x;
    int it = blockIdx.y, jt = blockIdx.z;
    if (jt > it) return;
    int b = bc >> 3, c = bc & 7;
    __shared__ float Cts[64][65];
    __shared__ float Bts[64][65];
    int t = threadIdx.x;
    int ti = t >> 4, tj = t & 15;
    float acc[4][4] = {};
    for (int k0 = 0; k0 < STATE; k0 += 64) {
        __syncthreads();
        for (int i = 0; i < 16; ++i) {
            int idx = t + i * 256;
            int r = idx >> 6, kc = idx & 63;
            Cts[r][kc] = xbc[(size_t)(b*SEQ + c*QCH + it*64 + r) * CONV_DIM + INTER + STATE + k0 + kc];
            Bts[r][kc] = xbc[(size_t)(b*SEQ + c*QCH + jt*64 + r) * CONV_DIM + INTER + k0 + kc];
        }
        __syncthreads();
#pragma unroll 16
        for (int k = 0; k < 64; ++k) {
            float cv[4], bv[4];
#pragma unroll
            for (int ii = 0; ii < 4; ++ii) cv[ii] = Cts[4*ti + ii][k];
#pragma unroll
            for (int jj = 0; jj < 4; ++jj) bv[jj] = Bts[4*tj + jj][k];
#pragma unroll
            for (int ii = 0; ii < 4; ++ii)
#pragma unroll
                for (int jj = 0; jj < 4; ++jj)
                    acc[ii][jj] = fmaf(cv[ii], bv[jj], acc[ii][jj]);
        }
    }
    for (int ii = 0; ii < 4; ++ii)
        for (int jj = 0; jj < 4; ++jj)
            CB[((size_t)bc * QCH + it*64 + 4*ti + ii) * QCH + jt*64 + 4*tj + jj] = acc[ii][jj];
}

// ---------------------------------------------------------------------------
// states[b,c,h,p,n] = sum_j B[j,n] * x[j,h,p] * dt[j] * exp(seg_last - seg[j])
// ---------------------------------------------------------------------------
__global__ __launch_bounds__(256)
void states_kernel(const float* __restrict__ xbc, const float* __restrict__ dt,
                   const float* __restrict__ seg, float* __restrict__ states) {
    int bid = blockIdx.x;
    int h = bid & 31, c = (bid >> 5) & 7, b = bid >> 8;
    __shared__ float Bsh[64][STATE];
    __shared__ float xws[64][PDIM];
    int t = threadIdx.x;
    int tp = t >> 4, tn = t & 15;
    float2 acc[4][4];
    for (int ii = 0; ii < 4; ++ii)
        for (int jj = 0; jj < 4; ++jj) acc[ii][jj] = make_float2(0.f, 0.f);
    float seg_last = seg[(size_t)(b*SEQ + c*QCH + QCH - 1) * NH + h];
    for (int j0 = 0; j0 < QCH; j0 += 64) {
        __syncthreads();
        for (int i = 0; i < 32; ++i) {
            int idx = t + i * 256;
            int r = idx >> 7, col = idx & 127;
            Bsh[r][col] = xbc[(size_t)(b*SEQ + c*QCH + j0 + r) * CONV_DIM + INTER + col];
        }
        for (int i = 0; i < 16; ++i) {
            int idx = t + i * 256;
            int r = idx >> 6, col = idx & 63;
            int bl = b*SEQ + c*QCH + j0 + r;
            float d = dt[bl * NH + h];
            float dec = expf(seg_last - seg[bl * NH + h]);
            xws[r][col] = xbc[(size_t)bl * CONV_DIM + h * PDIM + col] * d * dec;
        }
        __syncthreads();
#pragma unroll 8
        for (int j = 0; j < 64; ++j) {
            float xv[4];
#pragma unroll
            for (int ii = 0; ii < 4; ++ii) xv[ii] = xws[j][4*tp + ii];
            float2 bv[4];
#pragma unroll
            for (int jj = 0; jj < 4; ++jj) bv[jj] = *(const float2*)&Bsh[j][2*tn + 32*jj];
#pragma unroll
            for (int ii = 0; ii < 4; ++ii)
#pragma unroll
                for (int jj = 0; jj < 4; ++jj) {
                    acc[ii][jj].x = fmaf(xv[ii], bv[jj].x, acc[ii][jj].x);
                    acc[ii][jj].y = fmaf(xv[ii], bv[jj].y, acc[ii][jj].y);
                }
        }
    }
    size_t base = ((((size_t)b * NCHUNK + c) * NH + h) * PDIM) * STATE;
    for (int ii = 0; ii < 4; ++ii)
        for (int jj = 0; jj < 4; ++jj) {
            int p = 4*tp + ii, n = 2*tn + 32*jj;
            *(float2*)&states[base + (size_t)p * STATE + n] = acc[ii][jj];
        }
}

// ---------------------------------------------------------------------------
// In-place inter-chunk scan: states[c] <- carry;  carry = carry*dec[c]+st
// ---------------------------------------------------------------------------
__global__ void scan_kernel(float* __restrict__ states, const float* __restrict__ seg) {
    int tid = blockIdx.x * blockDim.x + threadIdx.x;
    int n = tid & 127, p = (tid >> 7) & 63, h = (tid >> 13) & 31, b = tid >> 18;
    float carry = 0.f;
    for (int c = 0; c < NCHUNK; ++c) {
        size_t idx = ((((size_t)b * NCHUNK + c) * NH + h) * PDIM + p) * STATE + n;
        float st = states[idx];
        states[idx] = carry;
        float dec = expf(seg[(size_t)(b*SEQ + c*QCH + QCH - 1) * NH + h]);
        carry = carry * dec + st;
    }
}

// ---------------------------------------------------------------------------
// Yd: y[i,h,p] = sum_{j<=i} CB[i,j]*exp(seg[i]-seg[j])*x[j,h,p]*dt[j] + D[h]*x[i,h,p]
// ---------------------------------------------------------------------------
__global__ __launch_bounds__(256)
void yd_kernel(const float* __restrict__ xbc, const float* __restrict__ dt,
               const float* __restrict__ seg, const float* __restrict__ CB,
               const float* __restrict__ Dv, float* __restrict__ y) {
    int bid = blockIdx.x;
    int it = bid & 3, h = (bid >> 2) & 31, c = (bid >> 7) & 7, b = bid >> 10;
    int i0 = it * 64;
    __shared__ float Ls[64][65];
    __shared__ float xdts[64][64];
    __shared__ float segi_s[64], segj_s[64];
    int t = threadIdx.x;
    int ti = t >> 4, tp = t & 15;
    float acc[4][4] = {};
    if (t < 64) segi_s[t] = seg[(size_t)(b*SEQ + c*QCH + i0 + t) * NH + h];
    for (int j0 = 0; j0 <= i0; j0 += 64) {
        __syncthreads();
        if (t < 64) segj_s[t] = seg[(size_t)(b*SEQ + c*QCH + j0 + t) * NH + h];
        for (int i = 0; i < 16; ++i) {
            int idx = t + i * 256;
            int r = idx >> 6, col = idx & 63;
            int bl = b*SEQ + c*QCH + j0 + r;
            xdts[r][col] = xbc[(size_t)bl * CONV_DIM + h * PDIM + col] * dt[bl * NH + h];
        }
        __syncthreads();
        for (int i = 0; i < 16; ++i) {
            int idx = t + i * 256;
            int r = idx >> 6, col = idx & 63;
            float v = 0.f;
            if (j0 + col <= i0 + r)
                v = CB[((size_t)(b*NCHUNK + c) * QCH + i0 + r) * QCH + j0 + col]
                    * expf(segi_s[r] - segj_s[col]);
            Ls[r][col] = v;
        }
        __syncthreads();
#pragma unroll 8
        for (int j = 0; j < 64; ++j) {
            float lv[4], xv[4];
#pragma unroll
            for (int ii = 0; ii < 4; ++ii) lv[ii] = Ls[4*ti + ii][j];
#pragma unroll
            for (int pp = 0; pp < 4; ++pp) xv[pp] = xdts[j][4*tp + pp];
#pragma unroll
            for (int ii = 0; ii < 4; ++ii)
#pragma unroll
                for (int pp = 0; pp < 4; ++pp)
                    acc[ii][pp] = fmaf(lv[ii], xv[pp], acc[ii][pp]);
        }
    }
    float Dh = Dv[h];
    for (int ii = 0; ii < 4; ++ii) {
        int bl = b*SEQ + c*QCH + i0 + 4*ti + ii;
        for (int pp = 0; pp < 4; ++pp) {
            int p = 4*tp + pp;
            float xval = xbc[(size_t)bl * CONV_DIM + h * PDIM + p];
            y[(size_t)bl * INTER + h * PDIM + p] = acc[ii][pp] + Dh * xval;
        }
    }
}

// ---------------------------------------------------------------------------
// Yo: y[i,h,p] += exp(seg[i,h]) * sum_n C[i,n] * prev[b,c,h,p,n]
// ---------------------------------------------------------------------------
__global__ __launch_bounds__(256)
void yo_kernel(const float* __restrict__ xbc, const float* __restrict__ seg,
               const float* __restrict__ prev, float* __restrict__ y) {
    int bid = blockIdx.x;
    int h = bid & 31, c = (bid >> 5) & 7, b = bid >> 8;
    __shared__ float prevT[STATE][PDIM + 1];
    __shared__ float Cs[32][STATE + 1];
    int t = threadIdx.x;
    size_t pbase = ((((size_t)b * NCHUNK + c) * NH + h) * PDIM) * STATE;
    for (int i = 0; i < 32; ++i) {
        int idx = t + i * 256;
        int n = idx & 127, p = idx >> 7;
        prevT[n][p] = prev[pbase + (size_t)p * STATE + n];
    }
    int ti = t >> 5, tp = t & 31;
    for (int i0 = 0; i0 < QCH; i0 += 32) {
        __syncthreads();
        for (int i = 0; i < 16; ++i) {
            int idx = t + i * 256;
            int n = idx & 127, r = idx >> 7;
            Cs[r][n] = xbc[(size_t)(b*SEQ + c*QCH + i0 + r) * CONV_DIM + INTER + STATE + n];
        }
        __syncthreads();
        float acc[4][2] = {};
#pragma unroll 4
        for (int n = 0; n < STATE; ++n) {
            float cv[4], pv[2];
#pragma unroll
            for (int ii = 0; ii < 4; ++ii) cv[ii] = Cs[4*ti + ii][n];
#pragma unroll
            for (int pp = 0; pp < 2; ++pp) pv[pp] = prevT[n][2*tp + pp];
#pragma unroll
            for (int ii = 0; ii < 4; ++ii)
#pragma unroll
                for (int pp = 0; pp < 2; ++pp)
                    acc[ii][pp] = fmaf(cv[ii], pv[pp], acc[ii][pp]);
        }
        for (int ii = 0; ii < 4; ++ii) {
            int bl = b*SEQ + c*QCH + i0 + 4*ti + ii;
            float e = expf(seg[(size_t)bl * NH + h]);
            for (int pp = 0; pp < 2; ++pp) {
                int p = 2*tp + pp;
                y[(size_t)bl * INTER + h * PDIM + p] += e * acc[ii][pp];
            }
        }
    }
}

// ---------------------------------------------------------------------------
// yg = y * silu(z); RMS-norm; * norm_weight; emit bf16 for out_proj GEMM.
// Contiguous 8 elems/thread, vectorized loads + 16B bf16 store.
// ---------------------------------------------------------------------------
__global__ __launch_bounds__(256)
void gatenorm_kernel(const float* __restrict__ y, const float* __restrict__ zx,
                     const float* __restrict__ nw, u16* __restrict__ ybf) {
    int bl = blockIdx.x;
    int t = threadIdx.x;
    const float* yrow = y  + (size_t)bl * INTER + t * 8;
    const float* zrow = zx + (size_t)bl * DPROJ + t * 8;
    float4 y0 = *(const float4*)yrow,       y1 = *(const float4*)(yrow + 4);
    float4 z0 = *(const float4*)zrow,       z1 = *(const float4*)(zrow + 4);
    float yv[8] = {y0.x,y0.y,y0.z,y0.w,y1.x,y1.y,y1.z,y1.w};
    float zv[8] = {z0.x,z0.y,z0.z,z0.w,z1.x,z1.y,z1.z,z1.w};
    float g[8];
    float ss = 0.f;
#pragma unroll
    for (int i = 0; i < 8; ++i) {
        g[i] = yv[i] * (zv[i] / (1.f + expf(-zv[i])));
        ss += g[i] * g[i];
    }
    for (int off = 32; off > 0; off >>= 1) ss += __shfl_xor(ss, off, 64);
    __shared__ float red[4];
    if ((t & 63) == 0) red[t >> 6] = ss;
    __syncthreads();
    float tot = red[0] + red[1] + red[2] + red[3];
    float scale = rsqrtf(tot / INTER + 1e-6f);
    const float* nwp = nw + t * 8;
    u16x8 o;
#pragma unroll
    for (int i = 0; i < 8; ++i) o[i] = f2bf(g[i] * scale * nwp[i]);
    *(u16x8*)&ybf[(size_t)bl * INTER + t * 8] = o;
}

// ---------------------------------------------------------------------------
extern "C" void kernel_launch(void* const* d_in, const int* in_sizes, int n_in,
                              void* d_out, int out_size, void* d_ws, size_t ws_size,
                              hipStream_t stream) {
    const float* hidden     = (const float*)d_in[0];
    const float* in_proj_w  = (const float*)d_in[1];
    const float* conv_w     = (const float*)d_in[2];
    const float* conv_b     = (const float*)d_in[3];
    const float* dt_bias    = (const float*)d_in[4];
    const float* A_log      = (const float*)d_in[5];
    const float* Dv         = (const float*)d_in[6];
    const float* norm_w     = (const float*)d_in[7];
    const float* out_proj_w = (const float*)d_in[8];
    float* out = (float*)d_out;

    float* ws     = (float*)d_ws;
    float* zx     = ws;                                    // BL*DPROJ
    float* xbc    = zx  + (size_t)BL * DPROJ;              // BL*CONV_DIM
    float* dtb    = xbc + (size_t)BL * CONV_DIM;           // BL*NH
    float* segb   = dtb + (size_t)BL * NH;                 // BL*NH
    float* CB     = segb + (size_t)BL * NH;                // 16*QCH*QCH
    float* states = CB  + (size_t)BATCH*NCHUNK*QCH*QCH;    // 2*8*32*64*128
    float* y      = states + (size_t)BATCH*NCHUNK*NH*PDIM*STATE; // BL*INTER
    // bf16 scratch, aliased into dead regions:
    //  Abf/Wbf live steps 1-4; states written step 5      -> alias states
    //  ybf live steps 9-10; xbc dead after step 8         -> alias xbc
    //  W2bf live steps 3-10: fresh tail allocation (+4.2 MB)
    u16* Abf  = (u16*)states;
    u16* Wbf  = (u16*)states + (size_t)BL * HID;
    u16* ybf  = (u16*)xbc;
    u16* W2bf = (u16*)(y + (size_t)BL * INTER);

    // 1-3. f32 -> bf16 conversions (weight pad rows zero-filled)
    cvt_bf16<<<(BL*HID)/2048, 256, 0, stream>>>(hidden, Abf, (long)BL*HID, (long)BL*HID);
    cvt_bf16<<<((long)DPROJ_PAD*HID)/2048, 256, 0, stream>>>(in_proj_w, Wbf,
        (long)DPROJ*HID, (long)DPROJ_PAD*HID);
    cvt_bf16<<<((long)HID*INTER)/2048, 256, 0, stream>>>(out_proj_w, W2bf,
        (long)HID*INTER, (long)HID*INTER);

    // 4. in_proj: zx(f32) = Abf @ Wbf^T
    gemm_nt_bf16<<<dim3(DPROJ_PAD/128, BL/128), 256, 0, stream>>>(
        (const __bf16*)Abf, (const __bf16*)Wbf, zx, BL, DPROJ, DPROJ, HID);
    // 5. depthwise conv + silu
    conv_silu_kernel<<<(BL * CONV_DIM) / 256, 256, 0, stream>>>(zx, conv_w, conv_b, xbc);
    // 6. dt + per-chunk cumsum
    dtseg_kernel<<<BATCH * NCHUNK * NH, 256, 0, stream>>>(zx, dt_bias, A_log, dtb, segb);
    // 7. CB per chunk
    cb_kernel<<<dim3(BATCH * NCHUNK, 4, 4), 256, 0, stream>>>(xbc, CB);
    // 8. chunk-local states (clobbers Abf/Wbf - dead)
    states_kernel<<<BATCH * NCHUNK * NH, 256, 0, stream>>>(xbc, dtb, segb, states);
    // 9. inter-chunk scan
    scan_kernel<<<(BATCH * NH * PDIM * STATE) / 256, 256, 0, stream>>>(states, segb);
    // 10. within-chunk contribution + D*x
    yd_kernel<<<BATCH * NCHUNK * NH * 4, 256, 0, stream>>>(xbc, dtb, segb, CB, Dv, y);
    // 11. state contribution
    yo_kernel<<<BATCH * NCHUNK * NH, 256, 0, stream>>>(xbc, segb, states, y);
    // 12. gate + RMS norm -> bf16 (clobbers xbc - dead)
    gatenorm_kernel<<<BL, 256, 0, stream>>>(y, zx, norm_w, ybf);
    // 13. out_proj -> d_out (f32)
    gemm_nt_bf16<<<dim3(HID/128, BL/128), 256, 0, stream>>>(
        (const __bf16*)ybf, (const __bf16*)W2bf, out, BL, HID, HID, INTER);
}

// Round 3
// 255.805 us; speedup vs baseline: 5.6843x; 2.0418x over previous
//
#include <hip/hip_runtime.h>

#define HID      1024
#define INTER    2048
#define STATE    128
#define NH       32
#define PDIM     64
#define KCONV    4
#define QCH      256
#define CONV_DIM (INTER + 2*STATE)      // 2304
#define DPROJ    (2*INTER + 2*STATE + NH) // 4384
#define DPROJ_PAD 4480
#define BATCH    2
#define SEQ      2048
#define NCHUNK   (SEQ / QCH)            // 8
#define BL       (BATCH * SEQ)          // 4096

typedef unsigned short u16;
typedef unsigned int   u32;
typedef u16 u16x8 __attribute__((ext_vector_type(8)));
typedef u16 u16x4 __attribute__((ext_vector_type(4)));
typedef float f32x4 __attribute__((ext_vector_type(4)));
typedef __bf16 bf16x8 __attribute__((ext_vector_type(8)));

static __device__ __forceinline__ u16 f2bf(float f) {
    u32 u = __float_as_uint(f);
    return (u16)((u + 0x7FFFu + ((u >> 16) & 1u)) >> 16);
}
static __device__ __forceinline__ float bf2f(u16 v) {
    return __uint_as_float(((u32)v) << 16);
}
static __device__ __forceinline__ void gload_lds16(const void* g, void* l) {
    __builtin_amdgcn_global_load_lds(
        (const __attribute__((address_space(1))) void*)g,
        (__attribute__((address_space(3))) void*)l, 16, 0, 0);
}
// swizzled LDS u16-index helpers (row-major tiles; byte XOR at 16B granularity)
static __device__ __forceinline__ int swz64(int row, int slot) {   // 64B rows
    return ((row * 64 + slot * 16) ^ (((row >> 1) & 3) << 4)) >> 1;
}
static __device__ __forceinline__ int swz128(int row, int slot) {  // 128B rows
    return ((row * 128 + slot * 16) ^ ((row & 7) << 4)) >> 1;
}

// ---------------------------------------------------------------------------
// f32 -> bf16 conversion, 8 elems/thread; zero-fills [n, ntot).
// ---------------------------------------------------------------------------
__global__ __launch_bounds__(256)
void cvt_bf16(const float* __restrict__ src, u16* __restrict__ dst,
              long n, long ntot) {
    long i = ((long)blockIdx.x * 256 + threadIdx.x) * 8;
    if (i >= ntot) return;
    u16x8 o;
    if (i < n) {
        float4 a = *(const float4*)&src[i];
        float4 b = *(const float4*)&src[i + 4];
        o[0] = f2bf(a.x); o[1] = f2bf(a.y); o[2] = f2bf(a.z); o[3] = f2bf(a.w);
        o[4] = f2bf(b.x); o[5] = f2bf(b.y); o[6] = f2bf(b.z); o[7] = f2bf(b.w);
    } else {
        o = (u16x8)0;
    }
    *(u16x8*)&dst[i] = o;
}

// ---------------------------------------------------------------------------
// bf16 MFMA GEMM:  C[M,Nstride](f32) = A[M,K] * W[Npad,K]^T  (128x128, BK=32)
// ---------------------------------------------------------------------------
__global__ __launch_bounds__(256)
void gemm_nt_bf16(const __bf16* __restrict__ A, const __bf16* __restrict__ W,
                  float* __restrict__ C, int M, int Nstride, int Nreal, int K) {
    __shared__ __attribute__((aligned(16))) __bf16 As[128 * 32];
    __shared__ __attribute__((aligned(16))) __bf16 Ws[128 * 32];
    const int bm = blockIdx.y * 128;
    const int bn = blockIdx.x * 128;
    const int t = threadIdx.x;
    const int lane = t & 63;
    const int wave = t >> 6;
    const int wr = wave >> 1, wc = wave & 1;
    const int fr = lane & 15;
    const int fq = lane >> 4;
    f32x4 acc[4][4];
#pragma unroll
    for (int m = 0; m < 4; ++m)
#pragma unroll
        for (int n = 0; n < 4; ++n) acc[m][n] = 0;

    const int r0 = t >> 2;
    const int sg = (t & 3) * 8;
    const __bf16* Ag = A + (size_t)(bm + r0) * K + sg;
    const __bf16* Wg = W + (size_t)(bn + r0) * K + sg;

    for (int k0 = 0; k0 < K; k0 += 32) {
        gload_lds16(Ag + k0,                  &As[t * 8]);
        gload_lds16(Ag + (size_t)64 * K + k0, &As[2048 + t * 8]);
        gload_lds16(Wg + k0,                  &Ws[t * 8]);
        gload_lds16(Wg + (size_t)64 * K + k0, &Ws[2048 + t * 8]);
        __syncthreads();
        bf16x8 af[4], bw[4];
#pragma unroll
        for (int m = 0; m < 4; ++m)
            af[m] = *(const bf16x8*)&As[(wr * 64 + m * 16 + fr) * 32 + fq * 8];
#pragma unroll
        for (int n = 0; n < 4; ++n)
            bw[n] = *(const bf16x8*)&Ws[(wc * 64 + n * 16 + fr) * 32 + fq * 8];
#pragma unroll
        for (int m = 0; m < 4; ++m)
#pragma unroll
            for (int n = 0; n < 4; ++n)
                acc[m][n] = __builtin_amdgcn_mfma_f32_16x16x32_bf16(
                    af[m], bw[n], acc[m][n], 0, 0, 0);
        __syncthreads();
    }
#pragma unroll
    for (int m = 0; m < 4; ++m)
#pragma unroll
        for (int n = 0; n < 4; ++n) {
            int col = bn + wc * 64 + n * 16 + fr;
            if (col >= Nreal) continue;
            int row0 = bm + wr * 64 + m * 16 + fq * 4;
#pragma unroll
            for (int r = 0; r < 4; ++r)
                C[(size_t)(row0 + r) * Nstride + col] = acc[m][n][r];
        }
}

// ---------------------------------------------------------------------------
// Fused depthwise conv(K=4)+silu + transpose/pack:
//   x part  -> xT[b*2048 + c][L] bf16  (c in [0,2048))
//   B part  -> Bbf[b*L + l][128] bf16  AND  BT[b*128 + n][L] bf16
//   C part  -> Cbf[b*L + l][128] bf16
// grid (ctile=36, ltile=32, b=2), block 256.
// ---------------------------------------------------------------------------
__global__ __launch_bounds__(256)
void convT_kernel(const float* __restrict__ zx,
                  const float* __restrict__ conv_w,
                  const float* __restrict__ conv_b,
                  u16* __restrict__ xT, u16* __restrict__ BT,
                  u16* __restrict__ Bbf, u16* __restrict__ Cbf) {
    __shared__ float s[64][65];
    const int c0 = blockIdx.x * 64;
    const int l0 = blockIdx.y * 64;
    const int b  = blockIdx.z;
    const int t  = threadIdx.x;
    const int j  = t & 63;        // channel within tile
    const int g  = t >> 6;        // row group (16 rows each)
    const int cg = c0 + j;        // channel in CONV_DIM
    const float w0 = conv_w[cg * 4 + 0], w1 = conv_w[cg * 4 + 1];
    const float w2 = conv_w[cg * 4 + 2], w3 = conv_w[cg * 4 + 3];
    const float bias = conv_b[cg];
    const float* col = zx + (size_t)b * SEQ * DPROJ + INTER + cg;
    int lbase = l0 + g * 16;
    float h3, h2, h1;
    h3 = (lbase - 3 >= 0) ? col[(size_t)(lbase - 3) * DPROJ] : 0.f;
    h2 = (lbase - 2 >= 0) ? col[(size_t)(lbase - 2) * DPROJ] : 0.f;
    h1 = (lbase - 1 >= 0) ? col[(size_t)(lbase - 1) * DPROJ] : 0.f;
#pragma unroll
    for (int k = 0; k < 16; ++k) {
        int l = lbase + k;
        float x0 = col[(size_t)l * DPROJ];
        float v = bias + h3 * w0 + h2 * w1 + h1 * w2 + x0 * w3;
        v = v / (1.f + __expf(-v));
        h3 = h2; h2 = h1; h1 = x0;
        s[g * 16 + k][j] = v;
        if (cg >= INTER) {  // straight bf16 copies of B / C
            int n = cg - INTER;
            if (n < STATE)
                Bbf[(size_t)(b * SEQ + l) * STATE + n] = f2bf(v);
            else
                Cbf[(size_t)(b * SEQ + l) * STATE + (n - STATE)] = f2bf(v);
        }
    }
    if (c0 >= INTER + STATE) return;   // C tiles: no transpose needed
    __syncthreads();
    // transposed write: out row rr = c within tile, 16 l per thread
    const int rr = t >> 2;
    const int lch = (t & 3) * 16;
    int cgout = c0 + rr;
    u16* orow;
    if (cgout < INTER) orow = xT + (size_t)(b * SEQ + cgout) * SEQ;
    else               orow = BT + (size_t)(b * STATE + (cgout - INTER)) * SEQ;
    u16x8 o0, o1;
#pragma unroll
    for (int e = 0; e < 8; ++e) o0[e] = f2bf(s[lch + e][rr]);
#pragma unroll
    for (int e = 0; e < 8; ++e) o1[e] = f2bf(s[lch + 8 + e][rr]);
    *(u16x8*)&orow[l0 + lch]     = o0;
    *(u16x8*)&orow[l0 + lch + 8] = o1;
}

// ---------------------------------------------------------------------------
// dt = softplus(dt_raw + dt_bias); seg = inclusive cumsum(dt * A) per chunk.
// ---------------------------------------------------------------------------
__global__ __launch_bounds__(256)
void dtseg_kernel(const float* __restrict__ zx,
                  const float* __restrict__ dt_bias,
                  const float* __restrict__ A_log,
                  float* __restrict__ dt_out,
                  float* __restrict__ seg_out) {
    int bid = blockIdx.x;
    int h = bid & 31, c = (bid >> 5) & 7, b = bid >> 8;
    int i = threadIdx.x;
    int bl = b * SEQ + c * QCH + i;
    float x = zx[(size_t)bl * DPROJ + INTER + CONV_DIM + h] + dt_bias[h];
    float dtv = (x > 20.f) ? x : log1pf(expf(x));
    dt_out[bl * NH + h] = dtv;
    float Ah = -expf(A_log[h]);
    __shared__ float s[QCH];
    s[i] = dtv * Ah;
    __syncthreads();
    for (int off = 1; off < QCH; off <<= 1) {
        float add = (i >= off) ? s[i - off] : 0.f;
        __syncthreads();
        s[i] += add;
        __syncthreads();
    }
    seg_out[bl * NH + h] = s[i];
}

// ---------------------------------------------------------------------------
// CB[bc,i,j] = sum_n C[i,n]*B[j,n] via MFMA. grid (jt=4, it=4, bc=16).
// ---------------------------------------------------------------------------
__global__ __launch_bounds__(256)
void cb_kernel(const u16* __restrict__ Cbf, const u16* __restrict__ Bbf,
               float* __restrict__ CB) {
    const int jt = blockIdx.x, it = blockIdx.y;
    if (jt > it) return;
    const int bc = blockIdx.z;
    const int b = bc >> 3, c = bc & 7;
    __shared__ __attribute__((aligned(16))) u16 Ct[64 * 32];
    __shared__ __attribute__((aligned(16))) u16 Bt[64 * 32];
    const int t = threadIdx.x;
    const int lane = t & 63, wave = t >> 6;
    const int wr = wave >> 1, wc = wave & 1;
    const int fr = lane & 15, fq = lane >> 4;
    const int l0 = b * SEQ + c * QCH;
    f32x4 acc[2][2];
#pragma unroll
    for (int m = 0; m < 2; ++m)
#pragma unroll
        for (int n = 0; n < 2; ++n) acc[m][n] = 0;
    const int srow = t >> 2, sslot = t & 3;
    for (int n0 = 0; n0 < STATE; n0 += 32) {
        gload_lds16(Cbf + (size_t)(l0 + it * 64 + srow) * STATE + n0 +
                        8 * (sslot ^ ((srow >> 1) & 3)), &Ct[t * 8]);
        gload_lds16(Bbf + (size_t)(l0 + jt * 64 + srow) * STATE + n0 +
                        8 * (sslot ^ ((srow >> 1) & 3)), &Bt[t * 8]);
        __syncthreads();
        bf16x8 af[2], bw[2];
#pragma unroll
        for (int m = 0; m < 2; ++m)
            af[m] = *(const bf16x8*)&Ct[swz64(wr * 32 + m * 16 + fr, fq)];
#pragma unroll
        for (int n = 0; n < 2; ++n)
            bw[n] = *(const bf16x8*)&Bt[swz64(wc * 32 + n * 16 + fr, fq)];
#pragma unroll
        for (int m = 0; m < 2; ++m)
#pragma unroll
            for (int n = 0; n < 2; ++n)
                acc[m][n] = __builtin_amdgcn_mfma_f32_16x16x32_bf16(
                    af[m], bw[n], acc[m][n], 0, 0, 0);
        __syncthreads();
    }
#pragma unroll
    for (int m = 0; m < 2; ++m)
#pragma unroll
        for (int n = 0; n < 2; ++n) {
            int i = it * 64 + wr * 32 + m * 16 + fq * 4;
            int jj = jt * 64 + wc * 32 + n * 16 + fr;
#pragma unroll
            for (int r = 0; r < 4; ++r)
                CB[((size_t)bc * QCH + i + r) * QCH + jj] = acc[m][n][r];
        }
}

// ---------------------------------------------------------------------------
// states[b,c,h,p,n] = sum_j x[j,p]*dt[j]*exp(seg_last-seg[j]) * B[j,n]
// A = xT (scaled) [64p x 32j], B = BT [128n x 32j]. grid 512.
// ---------------------------------------------------------------------------
__global__ __launch_bounds__(256)
void states_kernel(const u16* __restrict__ xT, const u16* __restrict__ BT,
                   const float* __restrict__ dt, const float* __restrict__ seg,
                   float* __restrict__ states) {
    int bid = blockIdx.x;
    int h = bid & 31, c = (bid >> 5) & 7, b = bid >> 8;
    __shared__ float dd[QCH];
    __shared__ __attribute__((aligned(16))) u16 At[64 * 32];
    __shared__ __attribute__((aligned(16))) u16 Bt[128 * 32];
    const int t = threadIdx.x;
    const int lane = t & 63, wave = t >> 6;
    const int wr = wave >> 1, wc = wave & 1;
    const int fr = lane & 15, fq = lane >> 4;
    const int l0 = b * SEQ + c * QCH;
    {
        float seg_last = seg[(size_t)(l0 + QCH - 1) * NH + h];
        dd[t] = dt[(size_t)(l0 + t) * NH + h] *
                __expf(seg_last - seg[(size_t)(l0 + t) * NH + h]);
    }
    __syncthreads();
    f32x4 acc[2][4];
#pragma unroll
    for (int m = 0; m < 2; ++m)
#pragma unroll
        for (int n = 0; n < 4; ++n) acc[m][n] = 0;
    const int ap = t >> 2, ajs = t & 3;
    const u16* xrow = xT + (size_t)(b * SEQ + h * PDIM + ap) * SEQ + c * QCH;
    for (int j0 = 0; j0 < QCH; j0 += 32) {
        // A-stage (reg: load, scale by dd, pack, swizzled write)
        u16x8 v = *(const u16x8*)&xrow[j0 + ajs * 8];
        u16x8 o;
#pragma unroll
        for (int e = 0; e < 8; ++e)
            o[e] = f2bf(bf2f(v[e]) * dd[j0 + ajs * 8 + e]);
        *(u16x8*)&At[swz64(ap, ajs)] = o;
        // B-stage via gload (pre-swizzled source)
#pragma unroll
        for (int q = 0; q < 2; ++q) {
            int chunk = t + 256 * q;
            int row = chunk >> 2, slot = chunk & 3;
            gload_lds16(BT + (size_t)(b * STATE + row) * SEQ + c * QCH + j0 +
                            8 * (slot ^ ((row >> 1) & 3)), &Bt[chunk * 8]);
        }
        __syncthreads();
        bf16x8 af[2], bw[4];
#pragma unroll
        for (int m = 0; m < 2; ++m)
            af[m] = *(const bf16x8*)&At[swz64(wr * 32 + m * 16 + fr, fq)];
#pragma unroll
        for (int n = 0; n < 4; ++n)
            bw[n] = *(const bf16x8*)&Bt[swz64(wc * 64 + n * 16 + fr, fq)];
#pragma unroll
        for (int m = 0; m < 2; ++m)
#pragma unroll
            for (int n = 0; n < 4; ++n)
                acc[m][n] = __builtin_amdgcn_mfma_f32_16x16x32_bf16(
                    af[m], bw[n], acc[m][n], 0, 0, 0);
        __syncthreads();
    }
    size_t base = ((((size_t)b * NCHUNK + c) * NH + h) * PDIM) * STATE;
#pragma unroll
    for (int m = 0; m < 2; ++m)
#pragma unroll
        for (int n = 0; n < 4; ++n) {
            int p = wr * 32 + m * 16 + fq * 4;
            int nn = wc * 64 + n * 16 + fr;
#pragma unroll
            for (int r = 0; r < 4; ++r)
                states[base + (size_t)(p + r) * STATE + nn] = acc[m][n][r];
        }
}

// ---------------------------------------------------------------------------
// Inter-chunk scan (in place) + bf16 copy of the carried (prev) states.
// ---------------------------------------------------------------------------
__global__ void scan_kernel(float* __restrict__ states,
                            const float* __restrict__ seg,
                            u16* __restrict__ prevbf) {
    int tid = blockIdx.x * blockDim.x + threadIdx.x;
    int n = tid & 127, p = (tid >> 7) & 63, h = (tid >> 13) & 31, b = tid >> 18;
    float carry = 0.f;
    for (int c = 0; c < NCHUNK; ++c) {
        size_t idx = ((((size_t)b * NCHUNK + c) * NH + h) * PDIM + p) * STATE + n;
        float st = states[idx];
        states[idx] = carry;
        prevbf[idx] = f2bf(carry);
        float dec = __expf(seg[(size_t)(b*SEQ + c*QCH + QCH - 1) * NH + h]);
        carry = carry * dec + st;
    }
}

// ---------------------------------------------------------------------------
// Fused Yo + Yd + D*x:
//   acc  = exp(seg_i) * (C @ prev^T)            (yo, K=STATE)
//   acc += M' @ x,  M'[i,j]=CB*exp(seg_i-seg_j)*dt_j (masked), j-tiles of 64
//   y[i, h*64+p] = acc + D[h]*x[i,p]
// grid 512 (b,c,h); wave w owns i rows {64m + 16w .. +15}, all 64 p cols.
// ---------------------------------------------------------------------------
__global__ __launch_bounds__(256)
void ydo_kernel(const u16* __restrict__ xT, const u16* __restrict__ Cbf,
                const u16* __restrict__ prevbf, const float* __restrict__ CB,
                const float* __restrict__ dt, const float* __restrict__ seg,
                const float* __restrict__ Dv, float* __restrict__ y) {
    int bid = blockIdx.x;
    int h = bid & 31, c = (bid >> 5) & 7, b = bid >> 8;
    __shared__ float seg_s[QCH], sge_s[QCH], dtv_s[QCH];
    __shared__ __attribute__((aligned(16))) u16 big[QCH * 64];   // M / Ct
    __shared__ __attribute__((aligned(16))) u16 small[64 * 64];  // Xt / Pv
    const int t = threadIdx.x;
    const int lane = t & 63, w = t >> 6;
    const int fr = lane & 15, fq = lane >> 4;
    const int l0 = b * SEQ + c * QCH;
    {
        float sv = seg[(size_t)(l0 + t) * NH + h];
        seg_s[t] = sv;
        sge_s[t] = __expf(sv);
        dtv_s[t] = dt[(size_t)(l0 + t) * NH + h];
    }
    __syncthreads();
    f32x4 acc[4][4];
#pragma unroll
    for (int m = 0; m < 4; ++m)
#pragma unroll
        for (int n = 0; n < 4; ++n) acc[m][n] = 0;

    // ---- Yo: C[256x128] @ prev^T[128x64], K-steps of 32 ----
    const size_t pvbase = ((((size_t)b * NCHUNK + c) * NH + h) * PDIM) * STATE;
    for (int ks = 0; ks < 4; ++ks) {
#pragma unroll
        for (int q = 0; q < 4; ++q) {
            int chunk = t + 256 * q;
            int row = chunk >> 2, slot = chunk & 3;
            gload_lds16(Cbf + (size_t)(l0 + row) * STATE + ks * 32 +
                            8 * (slot ^ ((row >> 1) & 3)), &big[chunk * 8]);
        }
        {
            int row = t >> 2, slot = t & 3;
            gload_lds16(prevbf + pvbase + (size_t)row * STATE + ks * 32 +
                            8 * (slot ^ ((row >> 1) & 3)), &small[t * 8]);
        }
        __syncthreads();
        bf16x8 af[4], bw[4];
#pragma unroll
        for (int m = 0; m < 4; ++m)
            af[m] = *(const bf16x8*)&big[swz64(64 * m + 16 * w + fr, fq)];
#pragma unroll
        for (int n = 0; n < 4; ++n)
            bw[n] = *(const bf16x8*)&small[swz64(16 * n + fr, fq)];
#pragma unroll
        for (int m = 0; m < 4; ++m)
#pragma unroll
            for (int n = 0; n < 4; ++n)
                acc[m][n] = __builtin_amdgcn_mfma_f32_16x16x32_bf16(
                    af[m], bw[n], acc[m][n], 0, 0, 0);
        __syncthreads();
    }
    // scale yo contribution by exp(seg_i)
#pragma unroll
    for (int m = 0; m < 4; ++m)
#pragma unroll
        for (int n = 0; n < 4; ++n)
#pragma unroll
            for (int r = 0; r < 4; ++r)
                acc[m][n][r] *= sge_s[64 * m + 16 * w + fq * 4 + r];

    // ---- Yd: M'[256 x 64-tile] @ x[64 x 64p], 4 j-tiles ----
    const float* CBrow = CB + (size_t)(b * NCHUNK + c) * QCH * QCH;
    for (int jt = 0; jt < 4; ++jt) {
        const int j0 = jt * 64;
        // build M rows [j0,256)
        const int mcol = t & 63;
        for (int r = j0 + (t >> 6); r < QCH; r += 4) {
            float v = 0.f;
            if (mcol <= r - j0)
                v = CBrow[(size_t)r * QCH + j0 + mcol] *
                    __expf(seg_s[r] - seg_s[j0 + mcol]) * dtv_s[j0 + mcol];
            big[((r * 128 + mcol * 2) ^ ((r & 7) << 4)) >> 1] = f2bf(v);
        }
        // stage x tile [64p][64j] (pre-swizzled source)
#pragma unroll
        for (int q = 0; q < 2; ++q) {
            int chunk = t + 256 * q;
            int row = chunk >> 3, slot = chunk & 7;
            gload_lds16(xT + (size_t)(b * SEQ + h * PDIM + row) * SEQ +
                            c * QCH + j0 + 8 * (slot ^ (row & 7)),
                        &small[chunk * 8]);
        }
        __syncthreads();
#pragma unroll
        for (int ks = 0; ks < 2; ++ks) {
#pragma unroll
            for (int m = 0; m < 4; ++m) {
                if (64 * m + 16 * w >= j0) {
                    bf16x8 af = *(const bf16x8*)
                        &big[swz128(64 * m + 16 * w + fr, ks * 4 + fq)];
#pragma unroll
                    for (int n = 0; n < 4; ++n) {
                        bf16x8 bw = *(const bf16x8*)
                            &small[swz128(16 * n + fr, ks * 4 + fq)];
                        acc[m][n] = __builtin_amdgcn_mfma_f32_16x16x32_bf16(
                            af, bw, acc[m][n], 0, 0, 0);
                    }
                }
            }
        }
        __syncthreads();
    }
    // ---- epilogue: + D*x, store ----
    const float Dh = Dv[h];
#pragma unroll
    for (int m = 0; m < 4; ++m) {
        int i = 64 * m + 16 * w + fq * 4;
#pragma unroll
        for (int n = 0; n < 4; ++n) {
            int p = 16 * n + fr;
            u16x4 xv = *(const u16x4*)&xT[(size_t)(b * SEQ + h * PDIM + p) * SEQ +
                                          c * QCH + i];
#pragma unroll
            for (int r = 0; r < 4; ++r)
                y[(size_t)(l0 + i + r) * INTER + h * PDIM + p] =
                    acc[m][n][r] + Dh * bf2f(xv[r]);
        }
    }
}

// ---------------------------------------------------------------------------
// yg = y * silu(z); RMS-norm; * norm_weight; emit bf16 for out_proj GEMM.
// ---------------------------------------------------------------------------
__global__ __launch_bounds__(256)
void gatenorm_kernel(const float* __restrict__ y, const float* __restrict__ zx,
                     const float* __restrict__ nw, u16* __restrict__ ybf) {
    int bl = blockIdx.x;
    int t = threadIdx.x;
    const float* yrow = y  + (size_t)bl * INTER + t * 8;
    const float* zrow = zx + (size_t)bl * DPROJ + t * 8;
    float4 y0 = *(const float4*)yrow,       y1 = *(const float4*)(yrow + 4);
    float4 z0 = *(const float4*)zrow,       z1 = *(const float4*)(zrow + 4);
    float yv[8] = {y0.x,y0.y,y0.z,y0.w,y1.x,y1.y,y1.z,y1.w};
    float zv[8] = {z0.x,z0.y,z0.z,z0.w,z1.x,z1.y,z1.z,z1.w};
    float g[8];
    float ss = 0.f;
#pragma unroll
    for (int i = 0; i < 8; ++i) {
        g[i] = yv[i] * (zv[i] / (1.f + expf(-zv[i])));
        ss += g[i] * g[i];
    }
    for (int off = 32; off > 0; off >>= 1) ss += __shfl_xor(ss, off, 64);
    __shared__ float red[4];
    if ((t & 63) == 0) red[t >> 6] = ss;
    __syncthreads();
    float tot = red[0] + red[1] + red[2] + red[3];
    float scale = rsqrtf(tot / INTER + 1e-6f);
    const float* nwp = nw + t * 8;
    u16x8 o;
#pragma unroll
    for (int i = 0; i < 8; ++i) o[i] = f2bf(g[i] * scale * nwp[i]);
    *(u16x8*)&ybf[(size_t)bl * INTER + t * 8] = o;
}

// ---------------------------------------------------------------------------
extern "C" void kernel_launch(void* const* d_in, const int* in_sizes, int n_in,
                              void* d_out, int out_size, void* d_ws, size_t ws_size,
                              hipStream_t stream) {
    const float* hidden     = (const float*)d_in[0];
    const float* in_proj_w  = (const float*)d_in[1];
    const float* conv_w     = (const float*)d_in[2];
    const float* conv_b     = (const float*)d_in[3];
    const float* dt_bias    = (const float*)d_in[4];
    const float* A_log      = (const float*)d_in[5];
    const float* Dv         = (const float*)d_in[6];
    const float* norm_w     = (const float*)d_in[7];
    const float* out_proj_w = (const float*)d_in[8];
    float* out = (float*)d_out;

    float* ws     = (float*)d_ws;
    float* zx     = ws;                                      // 17,956,864
    float* dtb    = zx   + (size_t)BL * DPROJ;               //    131,072
    float* segb   = dtb  + (size_t)BL * NH;                  //    131,072
    float* CB     = segb + (size_t)BL * NH;                  //  1,048,576
    float* states = CB   + (size_t)BATCH*NCHUNK*QCH*QCH;     // 16,777,216
    float* y      = states + (size_t)BATCH*NCHUNK*NH*PDIM*STATE; // 8,388,608
    float* tail   = y + (size_t)BL * INTER;
    // u16 buffers in the tail
    u16* xT     = (u16*)tail;                                // 8,388,608 u16
    u16* BT     = xT   + (size_t)BL * INTER;                 //   524,288
    u16* Bbf    = BT   + (size_t)BATCH * STATE * SEQ;        //   524,288
    u16* Cbf    = Bbf  + (size_t)BL * STATE;                 //   524,288
    u16* prevbf = Cbf  + (size_t)BL * STATE;                 // 16,777,216
    u16* W2bf   = prevbf + (size_t)BATCH*NCHUNK*NH*PDIM*STATE; // 2,097,152
    // aliases into dead regions
    u16* Abf = (u16*)states;                  // live only until in_proj GEMM
    u16* Wbf = (u16*)states + (size_t)BL * HID;
    u16* ybf = xT;                            // xT dead after ydo

    cvt_bf16<<<(BL*HID)/2048, 256, 0, stream>>>(hidden, Abf, (long)BL*HID, (long)BL*HID);
    cvt_bf16<<<((long)DPROJ_PAD*HID)/2048, 256, 0, stream>>>(in_proj_w, Wbf,
        (long)DPROJ*HID, (long)DPROJ_PAD*HID);
    cvt_bf16<<<((long)HID*INTER)/2048, 256, 0, stream>>>(out_proj_w, W2bf,
        (long)HID*INTER, (long)HID*INTER);

    gemm_nt_bf16<<<dim3(DPROJ_PAD/128, BL/128), 256, 0, stream>>>(
        (const __bf16*)Abf, (const __bf16*)Wbf, zx, BL, DPROJ, DPROJ, HID);

    dtseg_kernel<<<BATCH * NCHUNK * NH, 256, 0, stream>>>(zx, dt_bias, A_log, dtb, segb);
    convT_kernel<<<dim3(CONV_DIM/64, SEQ/64, BATCH), 256, 0, stream>>>(
        zx, conv_w, conv_b, xT, BT, Bbf, Cbf);
    cb_kernel<<<dim3(4, 4, BATCH*NCHUNK), 256, 0, stream>>>(Cbf, Bbf, CB);
    states_kernel<<<BATCH * NCHUNK * NH, 256, 0, stream>>>(xT, BT, dtb, segb, states);
    scan_kernel<<<(BATCH * NH * PDIM * STATE) / 256, 256, 0, stream>>>(states, segb, prevbf);
    ydo_kernel<<<BATCH * NCHUNK * NH, 256, 0, stream>>>(
        xT, Cbf, prevbf, CB, dtb, segb, Dv, y);
    gatenorm_kernel<<<BL, 256, 0, stream>>>(y, zx, norm_w, ybf);
    gemm_nt_bf16<<<dim3(HID/128, BL/128), 256, 0, stream>>>(
        (const __bf16*)ybf, (const __bf16*)W2bf, out, BL, HID, HID, INTER);
}